// Round 1
// baseline (63.809 us; speedup 1.0000x reference)
//
#include <hip/hip_runtime.h>
#include <math.h>

#define EPS_COS 1e-16f
#define EPS_NRM 1e-8f

// Problem constants (B,N,M) = (64, 2048, 256)
constexpr int B = 64;
constexpr int N = 2048;
constexpr int M = 256;
constexpr int CHUNK = 128;   // n-rows per block in K3

// ---------------------------------------------------------------------------
// K1: cosine similarity per (b,n) row. One 64-lane wave handles one row of
// 256 floats: lane i loads float4 at m = i*4. Shuffle-reduce 3 sums.
// ---------------------------------------------------------------------------
__global__ void k1_cos(const float* __restrict__ mem,
                       const float* __restrict__ kk,
                       float* __restrict__ cosv) {
    int gid  = blockIdx.x * blockDim.x + threadIdx.x;
    int row  = gid >> 6;          // (b*N + n)
    int lane = threadIdx.x & 63;
    if (row >= B * N) return;
    int b = row >> 11;            // row / N  (N = 2048)

    const float4 mv = *reinterpret_cast<const float4*>(mem + (size_t)row * M + lane * 4);
    const float4 kv = *reinterpret_cast<const float4*>(kk  + (size_t)b   * M + lane * 4);

    float m0 = mv.x + EPS_COS, m1 = mv.y + EPS_COS, m2 = mv.z + EPS_COS, m3 = mv.w + EPS_COS;
    float q0 = kv.x + EPS_COS, q1 = kv.y + EPS_COS, q2 = kv.z + EPS_COS, q3 = kv.w + EPS_COS;

    float dot = m0 * q0 + m1 * q1 + m2 * q2 + m3 * q3;
    float msq = m0 * m0 + m1 * m1 + m2 * m2 + m3 * m3;
    float ksq = q0 * q0 + q1 * q1 + q2 * q2 + q3 * q3;

#pragma unroll
    for (int off = 32; off; off >>= 1) {
        dot += __shfl_xor(dot, off);
        msq += __shfl_xor(msq, off);
        ksq += __shfl_xor(ksq, off);
    }
    if (lane == 0) {
        float mn = fmaxf(sqrtf(msq), EPS_NRM);
        float kn = fmaxf(sqrtf(ksq), EPS_NRM);
        cosv[row] = dot / (mn * kn);
    }
}

// ---------------------------------------------------------------------------
// K2: per-batch softmax over N, coef = w_r*(1-lu_prev), s1 = sum(w_r*w_w),
// and out init: out[b,m] = s1 * k[b,m].  One block (256 thr) per batch.
// ---------------------------------------------------------------------------
__global__ void k2_softmax(const float* __restrict__ cosv,
                           const float* __restrict__ w_prev,
                           const int*   __restrict__ lu_prev,
                           const float* __restrict__ g,
                           const float* __restrict__ kk,
                           float* __restrict__ coef,
                           float* __restrict__ out) {
    int b   = blockIdx.x;
    int tid = threadIdx.x;
    __shared__ float red[4];

    const float* c = cosv + (size_t)b * N;

    // ---- max ----
    float mx = -1e30f;
    for (int i = tid; i < N; i += 256) mx = fmaxf(mx, c[i]);
#pragma unroll
    for (int off = 32; off; off >>= 1) mx = fmaxf(mx, __shfl_xor(mx, off));
    if ((tid & 63) == 0) red[tid >> 6] = mx;
    __syncthreads();
    mx = fmaxf(fmaxf(red[0], red[1]), fmaxf(red[2], red[3]));
    __syncthreads();

    // ---- sum of exp ----
    float Z = 0.f;
    for (int i = tid; i < N; i += 256) Z += expf(c[i] - mx);
#pragma unroll
    for (int off = 32; off; off >>= 1) Z += __shfl_xor(Z, off);
    if ((tid & 63) == 0) red[tid >> 6] = Z;
    __syncthreads();
    Z = red[0] + red[1] + red[2] + red[3];
    float invZ = 1.0f / Z;
    __syncthreads();

    // ---- coef + s1 ----
    float gb = g[b];
    const float* wrp = w_prev + (size_t)b * 2 * N + N;   // w_prev[b,1,:]
    const int*   lup = lu_prev + (size_t)b * N;
    float*       cf  = coef    + (size_t)b * N;

    float s1 = 0.f;
    for (int i = tid; i < N; i += 256) {
        float wr = expf(c[i] - mx) * invZ;
        float lu = (float)lup[i];
        float ww = gb * wrp[i] + (1.0f - gb) * lu;
        s1 += wr * ww;
        cf[i] = wr * (1.0f - lu);
    }
#pragma unroll
    for (int off = 32; off; off >>= 1) s1 += __shfl_xor(s1, off);
    if ((tid & 63) == 0) red[tid >> 6] = s1;
    __syncthreads();
    s1 = red[0] + red[1] + red[2] + red[3];

    // out init (also clears harness poison): M == 256 == blockDim.x
    out[(size_t)b * M + tid] = s1 * kk[(size_t)b * M + tid];
}

// ---------------------------------------------------------------------------
// K3: read[b,m] += sum_{n in chunk} coef[b,n] * memory[b,n,m]
// block = 256 threads (one per m), grid = (N/CHUNK, B). coef chunk in LDS.
// ---------------------------------------------------------------------------
__global__ void k3_read(const float* __restrict__ mem,
                        const float* __restrict__ coef,
                        float* __restrict__ out) {
    int b  = blockIdx.y;
    int n0 = blockIdx.x * CHUNK;
    int m  = threadIdx.x;

    __shared__ float scf[CHUNK];
    if (m < CHUNK) scf[m] = coef[(size_t)b * N + n0 + m];
    __syncthreads();

    const float* mp = mem + ((size_t)b * N + n0) * M + m;
    float acc = 0.f;
#pragma unroll 8
    for (int i = 0; i < CHUNK; ++i)
        acc = fmaf(scf[i], mp[(size_t)i * M], acc);

    atomicAdd(out + (size_t)b * M + m, acc);
}

// ---------------------------------------------------------------------------
extern "C" void kernel_launch(void* const* d_in, const int* in_sizes, int n_in,
                              void* d_out, int out_size, void* d_ws, size_t ws_size,
                              hipStream_t stream) {
    const float* mem     = (const float*)d_in[0];  // (B,N,M)
    const float* kk      = (const float*)d_in[1];  // (B,M)
    const float* g       = (const float*)d_in[2];  // (B,1)
    // d_in[3] = gamma  -> dead for output
    const float* w_prev  = (const float*)d_in[4];  // (B,2,N)
    const int*   lu_prev = (const int*)  d_in[5];  // (B,N)
    // d_in[6] = n      -> dead for output (sort branch unused)
    float* out = (float*)d_out;                    // (B,M)

    float* cosv = (float*)d_ws;          // B*N floats
    float* coef = cosv + (size_t)B * N;  // B*N floats

    // K1: one wave per row; 4 waves per block
    k1_cos<<<(B * N) / 4, 256, 0, stream>>>(mem, kk, cosv);

    // K2: one block per batch
    k2_softmax<<<B, 256, 0, stream>>>(cosv, w_prev, lu_prev, g, kk, coef, out);

    // K3: weighted row-sum
    dim3 g3(N / CHUNK, B);
    k3_read<<<g3, 256, 0, stream>>>(mem, coef, out);
}

// Round 2
// 29.704 us; speedup vs baseline: 2.1482x; 2.1482x over previous
//
#include <hip/hip_runtime.h>
#include <math.h>

#define EPS_COS 1e-16f
#define EPS_NRM 1e-8f

// Problem constants (B,N,M) = (64, 2048, 256)
constexpr int B = 64;
constexpr int N = 2048;
constexpr int M = 256;

constexpr int BLK    = 512;          // threads per K1 block (8 waves)
constexpr int WAVES  = BLK / 64;     // 8
constexpr int CHUNK  = 256;          // rows of one batch per K1 block
constexpr int ROWS   = CHUNK / WAVES;// 32 rows per wave
constexpr int NCHUNK = N / CHUNK;    // 8 chunks per batch

// ---------------------------------------------------------------------------
// K1: single pass over memory. For each row (b,n):
//   cos = <mem_e, k_e> / (max(|mem_e|,eps)*max(|k_e|,eps))   (mem_e = mem+1e-16)
//   e   = exp(cos)                       (safe: cos in [-1,1], no max needed)
//   accumulate per-chunk partials:
//     pread[b,c,m] = sum_n e*(1-lu[n])*mem[b,n,m]
//     pZ[b,c]      = sum_n e
//     pS1[b,c]     = sum_n e*(g*w_r_prev[n] + (1-g)*lu[n])
// One wave per row-slice: lane i owns columns 4i..4i+3 (float4), so the row
// data used for the dot is reused in-register for the weighted accumulation.
// ---------------------------------------------------------------------------
__global__ __launch_bounds__(BLK)
void k1_fused(const float* __restrict__ mem,
              const float* __restrict__ kk,
              const float* __restrict__ g,
              const float* __restrict__ w_prev,
              const int*   __restrict__ lu_prev,
              float* __restrict__ pread,
              float* __restrict__ pZ,
              float* __restrict__ pS1)
{
    const int b    = blockIdx.y;
    const int c    = blockIdx.x;
    const int tid  = threadIdx.x;
    const int w    = tid >> 6;      // wave id 0..7
    const int lane = tid & 63;
    const int n0   = c * CHUNK;

    // k row (+eps) and its norm, once per wave
    float4 kv = *reinterpret_cast<const float4*>(kk + (size_t)b * M + lane * 4);
    kv.x += EPS_COS; kv.y += EPS_COS; kv.z += EPS_COS; kv.w += EPS_COS;
    float ksq = kv.x*kv.x + kv.y*kv.y + kv.z*kv.z + kv.w*kv.w;
#pragma unroll
    for (int off = 32; off; off >>= 1) ksq += __shfl_xor(ksq, off);
    const float kn = fmaxf(sqrtf(ksq), EPS_NRM);

    const float gb   = g[b];
    const float* wrp = w_prev + (size_t)b * 2 * N + N;  // w_prev[b,1,:]
    const int*   lup = lu_prev + (size_t)b * N;
    const float* base = mem + ((size_t)b * N + n0 + w) * M + lane * 4;

    float4 acc = make_float4(0.f, 0.f, 0.f, 0.f);
    float Zp = 0.f, s1p = 0.f;

    auto process = [&](int i, const float4& v) {
        float m0 = v.x + EPS_COS, m1 = v.y + EPS_COS;
        float m2 = v.z + EPS_COS, m3 = v.w + EPS_COS;
        float dot = m0*kv.x + m1*kv.y + m2*kv.z + m3*kv.w;
        float msq = m0*m0 + m1*m1 + m2*m2 + m3*m3;
#pragma unroll
        for (int off = 32; off; off >>= 1) {
            dot += __shfl_xor(dot, off);
            msq += __shfl_xor(msq, off);
        }
        const int n = n0 + w + WAVES * i;
        const float cosv = dot / (fmaxf(sqrtf(msq), EPS_NRM) * kn);
        const float e  = __expf(cosv);
        const float lu = (float)lup[n];
        const float ww = gb * wrp[n] + (1.f - gb) * lu;
        Zp += e;
        s1p = fmaf(e, ww, s1p);
        const float cw = e * (1.f - lu);   // mem_zeroed weight (uses raw mem)
        acc.x = fmaf(cw, v.x, acc.x);
        acc.y = fmaf(cw, v.y, acc.y);
        acc.z = fmaf(cw, v.z, acc.z);
        acc.w = fmaf(cw, v.w, acc.w);
    };

    // prefetch-1 double buffer over this wave's 32 rows (stride 8 rows)
    float4 cur = *reinterpret_cast<const float4*>(base);
#pragma unroll 4
    for (int i = 0; i < ROWS - 1; ++i) {
        float4 nxt = *reinterpret_cast<const float4*>(base + (size_t)(i + 1) * WAVES * M);
        process(i, cur);
        cur = nxt;
    }
    process(ROWS - 1, cur);

    // block reduce across the 8 waves
    __shared__ float sred[WAVES * M];   // 8 KiB
    __shared__ float sZ[WAVES], sS1[WAVES];
    *reinterpret_cast<float4*>(&sred[w * M + lane * 4]) = acc;
    if (lane == 0) { sZ[w] = Zp; sS1[w] = s1p; }
    __syncthreads();

    if (tid < M) {
        float r = 0.f;
#pragma unroll
        for (int q = 0; q < WAVES; ++q) r += sred[q * M + tid];
        pread[((size_t)b * NCHUNK + c) * M + tid] = r;
    }
    if (tid == 0) {
        float z = 0.f, s = 0.f;
#pragma unroll
        for (int q = 0; q < WAVES; ++q) { z += sZ[q]; s += sS1[q]; }
        pZ[b * NCHUNK + c]  = z;
        pS1[b * NCHUNK + c] = s;
    }
}

// ---------------------------------------------------------------------------
// K2: out[b,m] = (sum_c pread[b,c,m] + s1[b]*k[b,m]) / Z[b]
// One block (256 threads) per batch.
// ---------------------------------------------------------------------------
__global__ __launch_bounds__(M)
void k2_final(const float* __restrict__ pread,
              const float* __restrict__ pZ,
              const float* __restrict__ pS1,
              const float* __restrict__ kk,
              float* __restrict__ out)
{
    const int b = blockIdx.x;
    const int t = threadIdx.x;

    __shared__ float sZ, sS1;
    if (t < 64) {
        float z = (t < NCHUNK) ? pZ[b * NCHUNK + t]  : 0.f;
        float s = (t < NCHUNK) ? pS1[b * NCHUNK + t] : 0.f;
#pragma unroll
        for (int off = 32; off; off >>= 1) {
            z += __shfl_xor(z, off);
            s += __shfl_xor(s, off);
        }
        if (t == 0) { sZ = z; sS1 = s; }
    }
    __syncthreads();

    const float invZ = 1.f / sZ;
    const float* pr = pread + (size_t)b * NCHUNK * M + t;
    float sum = 0.f;
#pragma unroll
    for (int c2 = 0; c2 < NCHUNK; ++c2) sum += pr[(size_t)c2 * M];

    out[(size_t)b * M + t] = (sum + sS1 * kk[(size_t)b * M + t]) * invZ;
}

// ---------------------------------------------------------------------------
extern "C" void kernel_launch(void* const* d_in, const int* in_sizes, int n_in,
                              void* d_out, int out_size, void* d_ws, size_t ws_size,
                              hipStream_t stream) {
    const float* mem     = (const float*)d_in[0];  // (B,N,M)
    const float* kk      = (const float*)d_in[1];  // (B,M)
    const float* g       = (const float*)d_in[2];  // (B,1)
    // d_in[3] = gamma  -> dead for the returned output
    const float* w_prev  = (const float*)d_in[4];  // (B,2,N)
    const int*   lu_prev = (const int*)  d_in[5];  // (B,N)
    // d_in[6] = n      -> dead for the returned output (sort branch unused)
    float* out = (float*)d_out;                    // (B,M)

    float* pread = (float*)d_ws;                           // B*NCHUNK*M floats (512 KiB)
    float* pZ    = pread + (size_t)B * NCHUNK * M;         // B*NCHUNK
    float* pS1   = pZ + (size_t)B * NCHUNK;                // B*NCHUNK

    dim3 g1(NCHUNK, B);   // (8, 64) = 512 blocks
    k1_fused<<<g1, BLK, 0, stream>>>(mem, kk, g, w_prev, lu_prev, pread, pZ, pS1);
    k2_final<<<B, M, 0, stream>>>(pread, pZ, pS1, kk, out);
}

// Round 3
// 29.424 us; speedup vs baseline: 2.1686x; 1.0095x over previous
//
#include <hip/hip_runtime.h>
#include <math.h>

#define EPS_COS 1e-16f
#define EPS_NRM 1e-8f

// Problem constants (B,N,M) = (64, 2048, 256)
constexpr int B = 64;
constexpr int N = 2048;
constexpr int M = 256;

constexpr int BLK    = 256;            // threads per K1 block (4 waves)
constexpr int WAVES  = BLK / 64;       // 4
constexpr int CHUNK  = 128;            // rows of one batch per K1 block
constexpr int RPW    = CHUNK / WAVES;  // 32 rows per wave
constexpr int PAIRS  = RPW / 2;        // 16 row-pairs per wave
constexpr int NCHUNK = N / CHUNK;      // 16 chunks per batch

// ---------------------------------------------------------------------------
// K1: single pass over memory, half-wave row-pair layout.
// Lanes 0-31 process row (2i), lanes 32-63 row (2i+1). Each lane owns 8
// columns: [sub*4, sub*4+3] and [128+sub*4, 128+sub*4+3]. The dot/norm
// butterfly is 5 levels within each half-wave, covering both rows at once.
// Per-row results: e = exp(cos) (cos in [-1,1] -> no max-subtraction needed),
// accumulate pread += e*(1-lu)*mem_row, pZ += e, pS1 += e*w_w.
// ---------------------------------------------------------------------------
__global__ __launch_bounds__(BLK)
void k1_fused(const float* __restrict__ mem,
              const float* __restrict__ kk,
              const float* __restrict__ g,
              const float* __restrict__ w_prev,
              const int*   __restrict__ lu_prev,
              float* __restrict__ pread,
              float* __restrict__ pZ,
              float* __restrict__ pS1)
{
    const int b    = blockIdx.y;
    const int c    = blockIdx.x;
    const int tid  = threadIdx.x;
    const int w    = tid >> 6;       // wave id 0..3
    const int lane = tid & 63;
    const int half = lane >> 5;      // 0: row 2i, 1: row 2i+1
    const int sub  = lane & 31;

    // k fragments for this lane's 8 columns (+eps), and ||k_e||
    float4 ka = *reinterpret_cast<const float4*>(kk + (size_t)b * M + sub * 4);
    float4 kb = *reinterpret_cast<const float4*>(kk + (size_t)b * M + 128 + sub * 4);
    ka.x += EPS_COS; ka.y += EPS_COS; ka.z += EPS_COS; ka.w += EPS_COS;
    kb.x += EPS_COS; kb.y += EPS_COS; kb.z += EPS_COS; kb.w += EPS_COS;
    float ksq = ka.x*ka.x + ka.y*ka.y + ka.z*ka.z + ka.w*ka.w
              + kb.x*kb.x + kb.y*kb.y + kb.z*kb.z + kb.w*kb.w;
#pragma unroll
    for (int off = 16; off; off >>= 1) ksq += __shfl_xor(ksq, off);
    const float kn = fmaxf(sqrtf(ksq), EPS_NRM);

    const float gb   = g[b];
    const float* wrp = w_prev + (size_t)b * 2 * N + N;   // w_prev[b,1,:]
    const int*   lup = lu_prev + (size_t)b * N;

    const int rowbase = c * CHUNK + w * RPW;             // this wave's rows
    const float* p = mem + ((size_t)b * N + rowbase + half) * M + sub * 4;

    float4 accA = make_float4(0.f, 0.f, 0.f, 0.f);
    float4 accB = make_float4(0.f, 0.f, 0.f, 0.f);
    float Zp = 0.f, s1p = 0.f;

    auto process = [&](int i, const float4& va, const float4& vb) {
        float a0 = va.x + EPS_COS, a1 = va.y + EPS_COS;
        float a2 = va.z + EPS_COS, a3 = va.w + EPS_COS;
        float b0 = vb.x + EPS_COS, b1 = vb.y + EPS_COS;
        float b2 = vb.z + EPS_COS, b3 = vb.w + EPS_COS;
        float dot = a0*ka.x + a1*ka.y + a2*ka.z + a3*ka.w
                  + b0*kb.x + b1*kb.y + b2*kb.z + b3*kb.w;
        float msq = a0*a0 + a1*a1 + a2*a2 + a3*a3
                  + b0*b0 + b1*b1 + b2*b2 + b3*b3;
#pragma unroll
        for (int off = 16; off; off >>= 1) {
            dot += __shfl_xor(dot, off);
            msq += __shfl_xor(msq, off);
        }
        const int n = rowbase + 2 * i + half;
        const float cosv = dot / (fmaxf(sqrtf(msq), EPS_NRM) * kn);
        const float e  = __expf(cosv);
        const float lu = (float)lup[n];
        const float ww = gb * wrp[n] + (1.f - gb) * lu;
        Zp += e;
        s1p = fmaf(e, ww, s1p);
        const float cw = e * (1.f - lu);   // weight on raw mem row
        accA.x = fmaf(cw, va.x, accA.x);
        accA.y = fmaf(cw, va.y, accA.y);
        accA.z = fmaf(cw, va.z, accA.z);
        accA.w = fmaf(cw, va.w, accA.w);
        accB.x = fmaf(cw, vb.x, accB.x);
        accB.y = fmaf(cw, vb.y, accB.y);
        accB.z = fmaf(cw, vb.z, accB.z);
        accB.w = fmaf(cw, vb.w, accB.w);
    };

    // prefetch-2 pipeline over 16 row-pairs (row stride 2*M per pair)
    float4 va0 = *reinterpret_cast<const float4*>(p);
    float4 vb0 = *reinterpret_cast<const float4*>(p + 128);
    float4 va1 = *reinterpret_cast<const float4*>(p + 2 * M);
    float4 vb1 = *reinterpret_cast<const float4*>(p + 2 * M + 128);
#pragma unroll 2
    for (int i = 0; i < PAIRS - 2; ++i) {
        float4 va2 = *reinterpret_cast<const float4*>(p + (size_t)(i + 2) * 2 * M);
        float4 vb2 = *reinterpret_cast<const float4*>(p + (size_t)(i + 2) * 2 * M + 128);
        process(i, va0, vb0);
        va0 = va1; vb0 = vb1;
        va1 = va2; vb1 = vb2;
    }
    process(PAIRS - 2, va0, vb0);
    process(PAIRS - 1, va1, vb1);

    // merge the two half-waves (once per wave)
    accA.x += __shfl_xor(accA.x, 32); accA.y += __shfl_xor(accA.y, 32);
    accA.z += __shfl_xor(accA.z, 32); accA.w += __shfl_xor(accA.w, 32);
    accB.x += __shfl_xor(accB.x, 32); accB.y += __shfl_xor(accB.y, 32);
    accB.z += __shfl_xor(accB.z, 32); accB.w += __shfl_xor(accB.w, 32);
    Zp  += __shfl_xor(Zp, 32);
    s1p += __shfl_xor(s1p, 32);

    // block reduce across the 4 waves
    __shared__ float sred[WAVES * M];   // 4 KiB
    __shared__ float sZ[WAVES], sS1[WAVES];
    if (half == 0) {
        *reinterpret_cast<float4*>(&sred[w * M + sub * 4])       = accA;
        *reinterpret_cast<float4*>(&sred[w * M + 128 + sub * 4]) = accB;
    }
    if (lane == 0) { sZ[w] = Zp; sS1[w] = s1p; }
    __syncthreads();

    if (tid < M) {
        float r = 0.f;
#pragma unroll
        for (int q = 0; q < WAVES; ++q) r += sred[q * M + tid];
        pread[((size_t)b * NCHUNK + c) * M + tid] = r;
    }
    if (tid == 0) {
        float z = 0.f, s = 0.f;
#pragma unroll
        for (int q = 0; q < WAVES; ++q) { z += sZ[q]; s += sS1[q]; }
        pZ[b * NCHUNK + c]  = z;
        pS1[b * NCHUNK + c] = s;
    }
}

// ---------------------------------------------------------------------------
// K2: out[b,m] = (sum_c pread[b,c,m] + s1[b]*k[b,m]) / Z[b]
// One block (256 threads) per batch.
// ---------------------------------------------------------------------------
__global__ __launch_bounds__(M)
void k2_final(const float* __restrict__ pread,
              const float* __restrict__ pZ,
              const float* __restrict__ pS1,
              const float* __restrict__ kk,
              float* __restrict__ out)
{
    const int b = blockIdx.x;
    const int t = threadIdx.x;

    __shared__ float sZ, sS1;
    if (t < 64) {
        float z = (t < NCHUNK) ? pZ[b * NCHUNK + t]  : 0.f;
        float s = (t < NCHUNK) ? pS1[b * NCHUNK + t] : 0.f;
#pragma unroll
        for (int off = 32; off; off >>= 1) {
            z += __shfl_xor(z, off);
            s += __shfl_xor(s, off);
        }
        if (t == 0) { sZ = z; sS1 = s; }
    }
    __syncthreads();

    const float invZ = 1.f / sZ;
    const float* pr = pread + (size_t)b * NCHUNK * M + t;
    float sum = 0.f;
#pragma unroll
    for (int c2 = 0; c2 < NCHUNK; ++c2) sum += pr[(size_t)c2 * M];

    out[(size_t)b * M + t] = (sum + sS1 * kk[(size_t)b * M + t]) * invZ;
}

// ---------------------------------------------------------------------------
extern "C" void kernel_launch(void* const* d_in, const int* in_sizes, int n_in,
                              void* d_out, int out_size, void* d_ws, size_t ws_size,
                              hipStream_t stream) {
    const float* mem     = (const float*)d_in[0];  // (B,N,M)
    const float* kk      = (const float*)d_in[1];  // (B,M)
    const float* g       = (const float*)d_in[2];  // (B,1)
    // d_in[3] = gamma  -> dead for the returned output
    const float* w_prev  = (const float*)d_in[4];  // (B,2,N)
    const int*   lu_prev = (const int*)  d_in[5];  // (B,N)
    // d_in[6] = n      -> dead for the returned output (sort branch unused)
    float* out = (float*)d_out;                    // (B,M)

    float* pread = (float*)d_ws;                           // B*NCHUNK*M floats (1 MiB)
    float* pZ    = pread + (size_t)B * NCHUNK * M;         // B*NCHUNK
    float* pS1   = pZ + (size_t)B * NCHUNK;                // B*NCHUNK

    dim3 g1(NCHUNK, B);   // (16, 64) = 1024 blocks
    k1_fused<<<g1, BLK, 0, stream>>>(mem, kk, g, w_prev, lu_prev, pread, pZ, pS1);
    k2_final<<<B, M, 0, stream>>>(pread, pZ, pS1, kk, out);
}